// Round 1
// baseline (7382.795 us; speedup 1.0000x reference)
//
#include <hip/hip_runtime.h>
#include <math.h>

// Problem constants (fixed by reference): B=256, T=2048, D=64, U=128, 4U=512, COND=32
namespace {
constexpr int kB    = 256;
constexpr int kT    = 2048;
constexpr int kD    = 64;
constexpr int kU    = 128;
constexpr int kG    = 512;   // 4*U, gate width
constexpr int kCOND = 32;
}

__device__ __forceinline__ float sig_(float z) {
    return 1.0f / (1.0f + __expf(-z));
}
// overflow-safe tanh: tanh(z) = sign(z) * (1 - e^{-2|z|}) / (1 + e^{-2|z|})
__device__ __forceinline__ float tanh_(float z) {
    float ez = __expf(-2.0f * fabsf(z));
    float t  = (1.0f - ez) / (1.0f + ez);
    return copysignf(t, z);
}

// One workgroup per batch element; persistent over all T timesteps.
// Thread j in [0,512) owns gate column j: Wk[:,j] and Uk[:,j] in registers.
__global__ __launch_bounds__(kG, 2)
void lstm_persistent(const float* __restrict__ x,     // [B,T,D]
                     const float* __restrict__ cond,  // [B,COND]
                     const float* __restrict__ Wc,    // [COND,U]
                     const float* __restrict__ bc,    // [U]
                     const float* __restrict__ Wk,    // [D,4U]
                     const float* __restrict__ Uk,    // [U,4U]
                     const float* __restrict__ bias,  // [4U]
                     float* __restrict__ out) {       // [B,U]
    const int b = blockIdx.x;
    const int j = threadIdx.x;

    __shared__ float4 h4[kU / 4];   // h state, float4-aligned for ds_read_b128
    __shared__ float  g_s[kG];      // pre-activation gates for this step
    float* h_s = (float*)h4;

    // ---- preload this thread's weight columns into registers (coalesced) ----
    float wk[kD];
    float uk[kU];
#pragma unroll
    for (int d = 0; d < kD; ++d) wk[d] = Wk[d * kG + j];
#pragma unroll
    for (int u = 0; u < kU; ++u) uk[u] = Uk[u * kG + j];
    const float bj = bias[j];

    // ---- initial state: h0 = c0 = cond @ Wc + bc ----
    float c_reg = 0.0f;              // cell state, held by threads 0..127
    if (j < kU) {
        float a = bc[j];
        const float* cr = cond + b * kCOND;
#pragma unroll
        for (int k = 0; k < kCOND; ++k) a = fmaf(cr[k], Wc[k * kU + j], a);
        h_s[j] = a;
        c_reg  = a;
    }
    __syncthreads();

    const float* xb = x + (size_t)b * kT * kD;

#pragma unroll 1
    for (int t = 0; t < kT; ++t) {
        const float* xt = xb + t * kD;   // wave-uniform address -> scalar loads

        // g_j = bj + sum_u h[u]*Uk[u][j] + sum_d x_t[d]*Wk[d][j]
        // h-part first: LDS data is ready right after the barrier, hides x latency.
        float a0 = bj, a1 = 0.0f, a2 = 0.0f, a3 = 0.0f;
#pragma unroll
        for (int q = 0; q < kU / 4; ++q) {
            float4 hv = h4[q];           // broadcast ds_read_b128, conflict-free
            a0 = fmaf(hv.x, uk[4 * q + 0], a0);
            a1 = fmaf(hv.y, uk[4 * q + 1], a1);
            a2 = fmaf(hv.z, uk[4 * q + 2], a2);
            a3 = fmaf(hv.w, uk[4 * q + 3], a3);
        }
#pragma unroll
        for (int d = 0; d < kD; d += 4) {
            a0 = fmaf(xt[d + 0], wk[d + 0], a0);
            a1 = fmaf(xt[d + 1], wk[d + 1], a1);
            a2 = fmaf(xt[d + 2], wk[d + 2], a2);
            a3 = fmaf(xt[d + 3], wk[d + 3], a3);
        }
        g_s[j] = (a0 + a1) + (a2 + a3);
        __syncthreads();

        // gate combine: thread u < 128 owns state element u
        if (j < kU) {
            float iv = sig_(g_s[j]);
            float fv = sig_(g_s[kU + j]);
            float cb = tanh_(g_s[2 * kU + j]);
            float ov = sig_(g_s[3 * kU + j]);
            c_reg = fmaf(fv, c_reg, iv * cb);
            h_s[j] = ov * tanh_(c_reg);
        }
        __syncthreads();
    }

    if (j < kU) out[b * kU + j] = h_s[j];
}

extern "C" void kernel_launch(void* const* d_in, const int* in_sizes, int n_in,
                              void* d_out, int out_size, void* d_ws, size_t ws_size,
                              hipStream_t stream) {
    const float* x    = (const float*)d_in[0];
    const float* cond = (const float*)d_in[1];
    const float* Wc   = (const float*)d_in[2];
    const float* bc   = (const float*)d_in[3];
    const float* Wk   = (const float*)d_in[4];
    const float* Uk   = (const float*)d_in[5];
    const float* b    = (const float*)d_in[6];
    float* out = (float*)d_out;

    lstm_persistent<<<dim3(kB), dim3(kG), 0, stream>>>(x, cond, Wc, bc, Wk, Uk, b, out);
}

// Round 2
// 3591.359 us; speedup vs baseline: 2.0557x; 2.0557x over previous
//
#include <hip/hip_runtime.h>
#include <math.h>

// Problem constants (fixed by reference): B=256, T=2048, D=64, U=128, 4U=512, COND=32
namespace {
constexpr int kB    = 256;
constexpr int kT    = 2048;
constexpr int kD    = 64;
constexpr int kU    = 128;
constexpr int kG    = 512;   // 4*U, gate width
constexpr int kCOND = 32;
constexpr int kW    = 96;    // weights per thread (split-K)
}

__device__ __forceinline__ float sig_(float z) {
    return 1.0f / (1.0f + __expf(-z));
}
// overflow-safe tanh
__device__ __forceinline__ float tanh_(float z) {
    float ez = __expf(-2.0f * fabsf(z));
    float t  = (1.0f - ez) / (1.0f + ez);
    return copysignf(t, z);
}

// One workgroup (1024 threads) per batch element; persistent over T steps.
// tid = s*512 + j. Thread (j,0): owns Wk[:,j] (64) + Uk[0:32,j] (32).
//                  Thread (j,1): owns Uk[32:128,j] (96).
// 96 weights/thread + temps fits the hard 128-VGPR cap a 1024-thread WG
// imposes (16 waves resident -> 4 waves/SIMD), so the allocator cannot
// rematerialize weight loads into the loop (round-1 failure mode: 192
// weights -> remat -> 206 GB of L2 traffic -> 7.3 ms).
__global__ __launch_bounds__(1024)
__attribute__((amdgpu_waves_per_eu(4, 4)))
void lstm_persistent(const float* __restrict__ x,     // [B,T,D]
                     const float* __restrict__ cond,  // [B,COND]
                     const float* __restrict__ Wc,    // [COND,U]
                     const float* __restrict__ bc,    // [U]
                     const float* __restrict__ Wk,    // [D,4U]
                     const float* __restrict__ Uk,    // [U,4U]
                     const float* __restrict__ bias,  // [4U]
                     float* __restrict__ out) {       // [B,U]
    const int b   = blockIdx.x;
    const int tid = threadIdx.x;
    const int s   = tid >> 9;      // 0 or 1 (wave-uniform: waves 0-7 vs 8-15)
    const int j   = tid & (kG - 1);

    __shared__ float4 h4[kU / 4];      // h state (512 B), broadcast ds_read_b128
    __shared__ float  p_s[2][kG];      // per-half partial gate sums (4 KB)
    float* h_s = (float*)h4;

    // ---- preload this thread's 96 weights into registers (coalesced) ----
    float w[kW];
    if (s == 0) {
#pragma unroll
        for (int d = 0; d < kD; ++d) w[d] = Wk[d * kG + j];
#pragma unroll
        for (int u = 0; u < 32; ++u) w[kD + u] = Uk[u * kG + j];
    } else {
#pragma unroll
        for (int u = 0; u < kW; ++u) w[u] = Uk[(32 + u) * kG + j];
    }
    const float bj = (s == 0) ? bias[j] : 0.0f;

    // ---- initial state: h0 = c0 = cond @ Wc + bc (threads 0..127) ----
    float c_reg = 0.0f;
    if (tid < kU) {
        float a = bc[tid];
        const float* cr = cond + b * kCOND;
#pragma unroll
        for (int k = 0; k < kCOND; ++k) a = fmaf(cr[k], Wc[k * kU + tid], a);
        h_s[tid] = a;
        c_reg    = a;
    }
    __syncthreads();

    const float* xb = x + (size_t)b * kT * kD;

#pragma unroll 1
    for (int t = 0; t < kT; ++t) {
        float a0, a1, a2, a3;
        if (s == 0) {
            const float* xt = xb + t * kD;   // wave-uniform -> scalar loads
            a0 = bj; a1 = 0.0f; a2 = 0.0f; a3 = 0.0f;
            // h[0:32) from LDS (broadcast, conflict-free)
#pragma unroll
            for (int q = 0; q < 8; ++q) {
                float4 hv = h4[q];
                a0 = fmaf(hv.x, w[kD + 4 * q + 0], a0);
                a1 = fmaf(hv.y, w[kD + 4 * q + 1], a1);
                a2 = fmaf(hv.z, w[kD + 4 * q + 2], a2);
                a3 = fmaf(hv.w, w[kD + 4 * q + 3], a3);
            }
            // x_t part
#pragma unroll
            for (int d = 0; d < kD; d += 4) {
                a0 = fmaf(xt[d + 0], w[d + 0], a0);
                a1 = fmaf(xt[d + 1], w[d + 1], a1);
                a2 = fmaf(xt[d + 2], w[d + 2], a2);
                a3 = fmaf(xt[d + 3], w[d + 3], a3);
            }
        } else {
            a0 = 0.0f; a1 = 0.0f; a2 = 0.0f; a3 = 0.0f;
            // h[32:128) from LDS
#pragma unroll
            for (int q = 0; q < 24; ++q) {
                float4 hv = h4[8 + q];
                a0 = fmaf(hv.x, w[4 * q + 0], a0);
                a1 = fmaf(hv.y, w[4 * q + 1], a1);
                a2 = fmaf(hv.z, w[4 * q + 2], a2);
                a3 = fmaf(hv.w, w[4 * q + 3], a3);
            }
        }
        p_s[s][j] = (a0 + a1) + (a2 + a3);
        __syncthreads();

        // gate combine: thread u < 128 owns state element u
        if (tid < kU) {
            const int u = tid;
            float g0 = p_s[0][u]           + p_s[1][u];
            float g1 = p_s[0][kU + u]      + p_s[1][kU + u];
            float g2 = p_s[0][2 * kU + u]  + p_s[1][2 * kU + u];
            float g3 = p_s[0][3 * kU + u]  + p_s[1][3 * kU + u];
            float iv = sig_(g0);
            float fv = sig_(g1);
            float cb = tanh_(g2);
            float ov = sig_(g3);
            c_reg = fmaf(fv, c_reg, iv * cb);
            h_s[u] = ov * tanh_(c_reg);
        }
        __syncthreads();
    }

    if (tid < kU) out[b * kU + tid] = h_s[tid];
}

extern "C" void kernel_launch(void* const* d_in, const int* in_sizes, int n_in,
                              void* d_out, int out_size, void* d_ws, size_t ws_size,
                              hipStream_t stream) {
    const float* x    = (const float*)d_in[0];
    const float* cond = (const float*)d_in[1];
    const float* Wc   = (const float*)d_in[2];
    const float* bc   = (const float*)d_in[3];
    const float* Wk   = (const float*)d_in[4];
    const float* Uk   = (const float*)d_in[5];
    const float* b    = (const float*)d_in[6];
    float* out = (float*)d_out;

    lstm_persistent<<<dim3(kB), dim3(1024), 0, stream>>>(x, cond, Wc, bc, Wk, Uk, b, out);
}

// Round 3
// 2045.226 us; speedup vs baseline: 3.6098x; 1.7560x over previous
//
#include <hip/hip_runtime.h>
#include <math.h>

// B=256, T=2048, D=64, U=128, 4U=512, COND=32
namespace {
constexpr int kB    = 256;
constexpr int kT    = 2048;
constexpr int kD    = 64;
constexpr int kU    = 128;
constexpr int kG    = 512;
constexpr int kCOND = 32;
}

typedef _Float16 h2 __attribute__((ext_vector_type(2)));

__device__ __forceinline__ float sig_(float z) {
    return 1.0f / (1.0f + __expf(-z));
}
__device__ __forceinline__ float tanh_(float z) {
    float ez = __expf(-2.0f * fabsf(z));
    float t  = (1.0f - ez) / (1.0f + ez);
    return copysignf(t, z);
}

__device__ __forceinline__ float dot2_(h2 a, h2 b, float c) {
#if __has_builtin(__builtin_amdgcn_fdot2)
    return __builtin_amdgcn_fdot2(a, b, c, false);   // v_dot2_f32_f16: 2 MACs, fp32 acc
#else
    return fmaf((float)a.x, (float)b.x, fmaf((float)a.y, (float)b.y, c));
#endif
}

// Cross-lane add via DPP (pure VALU; avoids LDS-pipe ds_swizzle cost).
// 0xB1 = quad_perm [1,0,3,2] (xor1), 0x4E = quad_perm [2,3,0,1] (xor2),
// 0x128 = row_ror:8 (== xor8 within a 16-lane row).
template <int CTRL>
__device__ __forceinline__ float dpp_add_(float v) {
    int p = __builtin_amdgcn_update_dpp(0, __float_as_int(v), CTRL, 0xF, 0xF, true);
    return v + __int_as_float(p);
}

// One WG (1024 thr = 16 waves) per batch element, persistent over T steps.
// Per-thread: C=4 gate columns {j, j+128, j+256, j+384}, K-slice s of 8
// (24 of 192 K-elements: 8 x-elems + 16 h-elems), weights packed f16:
// 48 half2 VGPRs -> fits the 64-VGPR budget class, no spill possible.
// s lives in lane bits {0,1,3} so the split-K reduce is 3 DPP butterflies.
__global__ __launch_bounds__(1024, 4)
__attribute__((amdgpu_waves_per_eu(4, 4)))
void lstm_f16dot(const float* __restrict__ x,     // [B,T,D]
                 const float* __restrict__ cond,  // [B,COND]
                 const float* __restrict__ Wc,    // [COND,U]
                 const float* __restrict__ bc,    // [U]
                 const float* __restrict__ Wk,    // [D,4U]
                 const float* __restrict__ Uk,    // [U,4U]
                 const float* __restrict__ bias,  // [4U]
                 float* __restrict__ out) {       // [B,U]
    const int b    = blockIdx.x;
    const int tid  = threadIdx.x;
    const int lane = tid & 63;
    const int wav  = tid >> 6;
    const int s    = (lane & 3) | ((lane >> 1) & 4);        // lane bits 0,1,3
    const int jl   = ((lane >> 2) & 1) | ((lane >> 3) & 6); // lane bits 2,4,5
    const int j    = wav * 8 + jl;                          // colgroup 0..127

    // a = [x_t (64) ; h (128)] in f16.  g_s = fully-reduced gate preacts.
    __shared__ __align__(16) _Float16 a_s[kD + kU];
    __shared__ float g_s[kG];

    // ---- pack this thread's f16 weights: 4 cols x (4 x-pairs + 8 h-pairs) ----
    h2 wx[4][4];
    h2 wh[4][8];
#pragma unroll
    for (int i = 0; i < 4; ++i) {
        const int c = j + kU * i;
#pragma unroll
        for (int kk = 0; kk < 4; ++kk) {
            const int d = s * 8 + 2 * kk;
            h2 w; w.x = (_Float16)Wk[d * kG + c]; w.y = (_Float16)Wk[(d + 1) * kG + c];
            wx[i][kk] = w;
        }
#pragma unroll
        for (int kk = 0; kk < 8; ++kk) {
            const int u = s * 16 + 2 * kk;
            h2 w; w.x = (_Float16)Uk[u * kG + c]; w.y = (_Float16)Uk[(u + 1) * kG + c];
            wh[i][kk] = w;
        }
    }

    // ---- per-state-element constants + initial state (threads 0..127) ----
    float c_reg = 0.0f, h_out = 0.0f;
    float bi = 0.0f, bf = 0.0f, bcg = 0.0f, bo = 0.0f;
    if (tid < kU) {
        bi  = bias[tid];
        bf  = bias[kU + tid];
        bcg = bias[2 * kU + tid];
        bo  = bias[3 * kU + tid];
        float a = bc[tid];
        const float* cr = cond + b * kCOND;
#pragma unroll
        for (int k = 0; k < kCOND; ++k) a = fmaf(cr[k], Wc[k * kU + tid], a);
        c_reg = a;
        a_s[kD + tid] = (_Float16)a;      // h0
    }
    const float* xb = x + (size_t)b * kT * kD;
    if (tid >= kU && tid < kU + kD) {
        a_s[tid - kU] = (_Float16)xb[tid - kU];   // x_0
    }
    __syncthreads();

    union F4H { float4 f4; h2 h[4]; };

#pragma unroll 1
    for (int t = 0; t < kT; ++t) {
        // prefetch next x into a register (global load hidden under phase 1)
        float xv = 0.0f;
        if (tid >= kU && tid < kU + kD) {
            const int tn = (t + 1 < kT) ? (t + 1) : t;
            xv = xb[tn * kD + (tid - kU)];
        }

        // ---- phase 1: partial dots over this thread's K-slice, 4 columns ----
        const float4* a4 = (const float4*)a_s;
        F4H ux, uh0, uh1;
        ux.f4  = a4[s];            // x slice: 8 halves
        uh0.f4 = a4[8 + 2 * s];    // h slice: 16 halves
        uh1.f4 = a4[9 + 2 * s];

        float acc0 = 0.0f, acc1 = 0.0f, acc2 = 0.0f, acc3 = 0.0f;
#pragma unroll
        for (int kk = 0; kk < 4; ++kk) {
            acc0 = dot2_(ux.h[kk], wx[0][kk], acc0);
            acc1 = dot2_(ux.h[kk], wx[1][kk], acc1);
            acc2 = dot2_(ux.h[kk], wx[2][kk], acc2);
            acc3 = dot2_(ux.h[kk], wx[3][kk], acc3);
        }
#pragma unroll
        for (int kk = 0; kk < 4; ++kk) {
            acc0 = dot2_(uh0.h[kk], wh[0][kk], acc0);
            acc1 = dot2_(uh0.h[kk], wh[1][kk], acc1);
            acc2 = dot2_(uh0.h[kk], wh[2][kk], acc2);
            acc3 = dot2_(uh0.h[kk], wh[3][kk], acc3);
        }
#pragma unroll
        for (int kk = 0; kk < 4; ++kk) {
            acc0 = dot2_(uh1.h[kk], wh[0][4 + kk], acc0);
            acc1 = dot2_(uh1.h[kk], wh[1][4 + kk], acc1);
            acc2 = dot2_(uh1.h[kk], wh[2][4 + kk], acc2);
            acc3 = dot2_(uh1.h[kk], wh[3][4 + kk], acc3);
        }

        // split-K reduce across the 8 s-lanes (bits 0,1,3): DPP butterflies
        acc0 = dpp_add_<0xB1>(acc0);  acc0 = dpp_add_<0x4E>(acc0);  acc0 = dpp_add_<0x128>(acc0);
        acc1 = dpp_add_<0xB1>(acc1);  acc1 = dpp_add_<0x4E>(acc1);  acc1 = dpp_add_<0x128>(acc1);
        acc2 = dpp_add_<0xB1>(acc2);  acc2 = dpp_add_<0x4E>(acc2);  acc2 = dpp_add_<0x128>(acc2);
        acc3 = dpp_add_<0xB1>(acc3);  acc3 = dpp_add_<0x4E>(acc3);  acc3 = dpp_add_<0x128>(acc3);

        // lane with s==i publishes column j + 128*i
        if (s < 4) {
            float v = (s == 0) ? acc0 : (s == 1) ? acc1 : (s == 2) ? acc2 : acc3;
            g_s[j + kU * s] = v;
        }
        __syncthreads();

        // ---- phase 2: gates + state update (threads 0..127); x staging ----
        if (tid < kU) {
            float gi = g_s[tid]          + bi;
            float gf = g_s[kU + tid]     + bf;
            float gc = g_s[2 * kU + tid] + bcg;
            float go = g_s[3 * kU + tid] + bo;
            float iv = sig_(gi);
            float fv = sig_(gf);
            float cb = tanh_(gc);
            float ov = sig_(go);
            c_reg = fmaf(fv, c_reg, iv * cb);
            h_out = ov * tanh_(c_reg);
            a_s[kD + tid] = (_Float16)h_out;
        } else if (tid < kU + kD) {
            a_s[tid - kU] = (_Float16)xv;
        }
        __syncthreads();
    }

    if (tid < kU) out[b * kU + tid] = h_out;
}

extern "C" void kernel_launch(void* const* d_in, const int* in_sizes, int n_in,
                              void* d_out, int out_size, void* d_ws, size_t ws_size,
                              hipStream_t stream) {
    const float* x    = (const float*)d_in[0];
    const float* cond = (const float*)d_in[1];
    const float* Wc   = (const float*)d_in[2];
    const float* bc   = (const float*)d_in[3];
    const float* Wk   = (const float*)d_in[4];
    const float* Uk   = (const float*)d_in[5];
    const float* b    = (const float*)d_in[6];
    float* out = (float*)d_out;

    lstm_f16dot<<<dim3(kB), dim3(1024), 0, stream>>>(x, cond, Wc, bc, Wk, Uk, b, out);
}